// Round 2
// baseline (383.137 us; speedup 1.0000x reference)
//
#include <hip/hip_runtime.h>
#include <math.h>

#define HID 128
#define CAP 96       // per-node bucket capacity; deg ~ Poisson(32), P(>96) ~ 1e-18
#define TILE 8192    // edges per partition block
#define WSH 9        // coarse bucket = 512-node window
#define BUKCAP 24576 // per-bucket record capacity
#define NW 8         // source windows (16384 nodes = 2 MiB of g8 each)

typedef unsigned int uint;
typedef unsigned short ushort;
typedef float f32x2 __attribute__((ext_vector_type(2)));
typedef float f32x4 __attribute__((ext_vector_type(4)));
typedef short bf16x8 __attribute__((ext_vector_type(8)));  // 8 bf16 in 4 VGPRs

// ---- bf16 helpers ----
__device__ inline ushort f2bf(float f) {
    uint u = __float_as_uint(f);
    return (ushort)((u + 0x7fffu + ((u >> 16) & 1u)) >> 16);
}
__device__ inline uint packbf(float a, float b) {
    return (uint)f2bf(a) | ((uint)f2bf(b) << 16);
}
__device__ inline bf16x8 as_bf16x8(uint4 u) {
    union { uint4 a; bf16x8 b; } c;
    c.a = u;
    return c.b;
}

// ---- fp8 e4m3 helpers (HW converts, RNE+sat) ----
__device__ inline f32x2 fp8lo(uint q) { return __builtin_amdgcn_cvt_pk_f32_fp8(q, false); }
__device__ inline f32x2 fp8hi(uint q) { return __builtin_amdgcn_cvt_pk_f32_fp8(q, true); }
__device__ inline uint pack4fp8(float a, float b, float c, float d) {
    int t = __builtin_amdgcn_cvt_pk_fp8_f32(a, b, 0, false);
    return (uint)__builtin_amdgcn_cvt_pk_fp8_f32(c, d, t, true);
}

// ---------------- two-phase binning (no per-edge global atomics) ----------------

// Phase A: LDS histogram over an 8192-edge tile, one global atomic per touched
// bucket, packed records written as ~41-edge runs.
__global__ void __launch_bounds__(256) k_part(const int* __restrict__ row,
                                              const int* __restrict__ col,
                                              int* __restrict__ bukCur,
                                              uint* __restrict__ recs, int E) {
    __shared__ int hist[256];
    __shared__ int hist2[256];
    __shared__ uint base[256];
    int t = threadIdx.x;
    hist[t] = 0;
    hist2[t] = 0;
    __syncthreads();
    int i0 = blockIdx.x * TILE;
    int i1 = min(E, i0 + TILE);
    for (int i = i0 + t; i < i1; i += 256) {
        int b = col[i] >> WSH;
        atomicAdd(&hist[b], 1);
    }
    __syncthreads();
    if (hist[t] > 0) base[t] = (uint)atomicAdd(&bukCur[t], hist[t]);
    __syncthreads();
    for (int i = i0 + t; i < i1; i += 256) {
        int c = col[i];
        int b = c >> WSH;
        uint p = (uint)atomicAdd(&hist2[b], 1);
        uint idx = base[b] + p;
        if (idx < BUKCAP)
            recs[(size_t)b * BUKCAP + idx] = (uint)row[i] | ((uint)(c & 511) << 17);
    }
}

// Phase B v2: one block per bucket; per-(node,window) cursors in LDS so each
// node's ebin segment is ordered by SOURCE WINDOW (r>>14).  k_agg then sweeps
// g8 windows 0..7 in order -> instantaneous gather working set ~2-6 MB, mostly
// L2-resident per XCD (vs random access over the full 12.8 MB table).
// Two passes over bucket records: count -> per-node exclusive scan -> place.
// Fused prep tail unchanged: dinv + pk0 from in-LDS totals.
__global__ void __launch_bounds__(256) k_fbin(const uint* __restrict__ recs,
                                              const int* __restrict__ bukCur,
                                              const float* __restrict__ x,
                                              int* __restrict__ cnt,
                                              int* __restrict__ ebin,
                                              float* __restrict__ dinv,
                                              float2* __restrict__ pk0, int N) {
    __shared__ int lcnt[512 * NW];   // 16 KB: counts -> cursors
    __shared__ int ltot[512];
    int b = blockIdx.x;
    int t = threadIdx.x;
    for (int i = t; i < 512 * NW; i += 256) lcnt[i] = 0;
    __syncthreads();
    int n = min(bukCur[b], BUKCAP);
    const uint* rp = recs + (size_t)b * BUKCAP;
    int cbase = b << WSH;
    // pass 1: per-(node,window) histogram
    for (int j = t; j < n; j += 256) {
        uint u = rp[j];
        int r = (int)(u & 0x1FFFFu);
        int cl = (int)(u >> 17);
        atomicAdd(&lcnt[cl * NW + (r >> 14)], 1);
    }
    __syncthreads();
    // per-node exclusive scan of the NW counters (thread t owns nodes t, t+256)
#pragma unroll
    for (int s = 0; s < 2; ++s) {
        int cl = t + s * 256;
        int* p = &lcnt[cl * NW];
        int off = 0;
#pragma unroll
        for (int w = 0; w < NW; ++w) { int cw = p[w]; p[w] = off; off += cw; }
        ltot[cl] = off;
    }
    __syncthreads();
    // pass 2: window-ordered placement (records L2-hot from pass 1)
    for (int j = t; j < n; j += 256) {
        uint u = rp[j];
        int r = (int)(u & 0x1FFFFu);
        int cl = (int)(u >> 17);
        int p = atomicAdd(&lcnt[cl * NW + (r >> 14)], 1);
        if (p < CAP) ebin[(size_t)(cbase + cl) * CAP + p] = r << 5;
    }
    // fused prep tail
#pragma unroll
    for (int s = 0; s < 2; ++s) {
        int cl = t + s * 256;
        int c = cbase + cl;
        if (c < N) {
            int tot = ltot[cl];
            cnt[c] = tot;
            float d = rsqrtf((float)tot + 1.0f);  // +1 self-loop
            dinv[c] = d;
            pk0[c] = make_float2(d, d * x[c]);
        }
    }
}

// ---------------- fused W-prep: u/v (layer-0 analytic) + B-fragments ----------------

__global__ void k_wprep(const float* __restrict__ W_emb, const float* __restrict__ b_emb,
                        const float* __restrict__ W_gnn,
                        float* __restrict__ u, float* __restrict__ v,
                        uint4* __restrict__ wfrag) {
    int b = blockIdx.x;
    int t = threadIdx.x;
    if (b < 16) {
        int gid = b * 256 + t;   // 0..4095
        int l = gid >> 11;
        int rem = gid & 2047;
        int kb = rem >> 9;
        int nt = (rem >> 6) & 7;
        int lane = rem & 63;
        int k0 = kb * 32 + (lane >> 4) * 8;
        int n = nt * 16 + (lane & 15);
        const float* Wp = W_gnn + (size_t)(l + 1) * HID * HID;
        uint4 o;
        o.x = packbf(Wp[(k0 + 0) * HID + n], Wp[(k0 + 1) * HID + n]);
        o.y = packbf(Wp[(k0 + 2) * HID + n], Wp[(k0 + 3) * HID + n]);
        o.z = packbf(Wp[(k0 + 4) * HID + n], Wp[(k0 + 5) * HID + n]);
        o.w = packbf(Wp[(k0 + 6) * HID + n], Wp[(k0 + 7) * HID + n]);
        wfrag[gid] = o;
    } else if (t < HID) {
        float su = 0.f, sv = 0.f;
        for (int k = 0; k < HID; ++k) {
            float w = W_gnn[k * HID + t];
            su = fmaf(W_emb[k], w, su);
            sv = fmaf(b_emb[k], w, sv);
        }
        u[t] = su;
        v[t] = sv;
    }
}

// ---------------- layer 0: fused scalar-agg + h1 (g8 output) ----------------

__global__ void __launch_bounds__(256) k_sagg(const int* __restrict__ cnt,
                                              const int* __restrict__ ebin,
                                              const float* __restrict__ x,
                                              const float* __restrict__ dinv,
                                              const float2* __restrict__ pk0,
                                              const float* __restrict__ u,
                                              const float* __restrict__ v,
                                              const float* __restrict__ b0,
                                              uint* __restrict__ g8, int N) {
    __shared__ float sS0[256], sS1[256], sDc[256];
    int t = threadIdx.x;
    int c0 = blockIdx.x * 256;
    int c = c0 + t;
    if (c < N) {
        float dc = dinv[c];
        float A = 0.f, B = 0.f;
        int n = min(cnt[c], CAP);
        const int* bp = ebin + (size_t)c * CAP;
        int k = 0;
        for (; k + 4 <= n; k += 4) {
            float2 p0 = pk0[bp[k] >> 5], p1 = pk0[bp[k + 1] >> 5];
            float2 p2 = pk0[bp[k + 2] >> 5], p3 = pk0[bp[k + 3] >> 5];
            A += (p0.x + p1.x) + (p2.x + p3.x);
            B += (p0.y + p1.y) + (p2.y + p3.y);
        }
        for (; k < n; ++k) {
            float2 p = pk0[bp[k] >> 5];
            A += p.x;
            B += p.y;
        }
        float d2 = dc * dc;
        sS0[t] = fmaf(dc, A, d2);
        sS1[t] = fmaf(dc, B, d2 * x[c]);
        sDc[t] = dc;
    }
    __syncthreads();
    int nloc = min(256, N - c0);
    int total = nloc * 32;
    for (int gid = t; gid < total; gid += 256) {
        int lc = gid >> 5;
        int j = (gid & 31) * 4;
        float t1 = sS1[lc], t0 = sS0[lc], dc = sDc[lc];
        float v0 = fmaxf(fmaf(t1, u[j + 0], fmaf(t0, v[j + 0], b0[j + 0])), 0.f);
        float v1 = fmaxf(fmaf(t1, u[j + 1], fmaf(t0, v[j + 1], b0[j + 1])), 0.f);
        float v2 = fmaxf(fmaf(t1, u[j + 2], fmaf(t0, v[j + 2], b0[j + 2])), 0.f);
        float v3 = fmaxf(fmaf(t1, u[j + 3], fmaf(t0, v[j + 3], b0[j + 3])), 0.f);
        g8[(size_t)(c0 + lc) * 32 + (gid & 31)] = pack4fp8(dc * v0, dc * v1, dc * v2, dc * v3);
    }
}

// ---------------- aggregate: pure gather-add of pre-scaled g8 ----------------
// quarter-wave per row (16 lanes x dwordx2) -> 4 rows per load instruction,
// 16 rows in flight per unrolled step.  Self row folded in as offset index 0.
// Edge lists are source-window-ordered (k_fbin v2) -> sweeping gather.

__global__ void __launch_bounds__(256) k_agg(const int* __restrict__ cnt,
                                             const int* __restrict__ ebin,
                                             const float* __restrict__ dinv,
                                             const uint* __restrict__ g8,
                                             uint* __restrict__ a, int N) {
    int wave = (blockIdx.x * 256 + threadIdx.x) >> 6;
    if (wave >= N) return;
    int lane = threadIdx.x & 63;
    int c = wave;
    int ql = lane & 15;
    int qg = lane >> 4;
    const uint* __restrict__ gq = g8 + ql * 2;   // this lane's 8B column slice

    f32x2 a0 = {0.f, 0.f}, a1 = {0.f, 0.f}, a2 = {0.f, 0.f}, a3 = {0.f, 0.f};

    int n = min(cnt[c], CAP);
    int total = n + 1;                                        // + self row
    const int* __restrict__ bp = ebin + (size_t)c * CAP - 1;  // bp[gi], gi>=1

    for (int base = 0; base < total; base += 64) {
        int cw = min(total - base, 64);
        int gi = base + lane;
        int ro = 0;
        if (lane < cw) ro = (gi == 0) ? (c << 5) : bp[gi];
        int j = 0;
        for (; j + 16 <= cw; j += 16) {
            int o0 = __shfl(ro, j + qg);
            int o1 = __shfl(ro, j + 4 + qg);
            int o2 = __shfl(ro, j + 8 + qg);
            int o3 = __shfl(ro, j + 12 + qg);
            uint2 q0 = *(const uint2*)(gq + o0);
            uint2 q1 = *(const uint2*)(gq + o1);
            uint2 q2 = *(const uint2*)(gq + o2);
            uint2 q3 = *(const uint2*)(gq + o3);
            a0 += fp8lo(q0.x); a1 += fp8hi(q0.x); a2 += fp8lo(q0.y); a3 += fp8hi(q0.y);
            a0 += fp8lo(q1.x); a1 += fp8hi(q1.x); a2 += fp8lo(q1.y); a3 += fp8hi(q1.y);
            a0 += fp8lo(q2.x); a1 += fp8hi(q2.x); a2 += fp8lo(q2.y); a3 += fp8hi(q2.y);
            a0 += fp8lo(q3.x); a1 += fp8hi(q3.x); a2 += fp8lo(q3.y); a3 += fp8hi(q3.y);
        }
        for (; j + 4 <= cw; j += 4) {
            int o0 = __shfl(ro, j + qg);
            uint2 q0 = *(const uint2*)(gq + o0);
            a0 += fp8lo(q0.x); a1 += fp8hi(q0.x); a2 += fp8lo(q0.y); a3 += fp8hi(q0.y);
        }
        if (j < cw) {   // 1..3 leftover edges; clamped lanes re-read a hot row, zeroed
            int e = j + qg;
            int o0 = __shfl(ro, min(e, cw - 1));
            uint2 q0 = *(const uint2*)(gq + o0);
            if (e >= cw) { q0.x = 0u; q0.y = 0u; }
            a0 += fp8lo(q0.x); a1 += fp8hi(q0.x); a2 += fp8lo(q0.y); a3 += fp8hi(q0.y);
        }
    }

    // reduce the 4 quarter-partials (columns ql*8..ql*8+7 live in every quarter)
    float r0 = a0.x, r1 = a0.y, r2 = a1.x, r3 = a1.y;
    float r4 = a2.x, r5 = a2.y, r6 = a3.x, r7 = a3.y;
#pragma unroll
    for (int m = 16; m <= 32; m <<= 1) {
        r0 += __shfl_xor(r0, m); r1 += __shfl_xor(r1, m);
        r2 += __shfl_xor(r2, m); r3 += __shfl_xor(r3, m);
        r4 += __shfl_xor(r4, m); r5 += __shfl_xor(r5, m);
        r6 += __shfl_xor(r6, m); r7 += __shfl_xor(r7, m);
    }
    if (qg == 0) {
        float dc = dinv[c];
        uint4 o;
        o.x = packbf(dc * r0, dc * r1);
        o.y = packbf(dc * r2, dc * r3);
        o.z = packbf(dc * r4, dc * r5);
        o.w = packbf(dc * r6, dc * r7);
        ((uint4*)(a + (size_t)c * 64))[ql] = o;
    }
}

// ---------------- MFMA GEMM ----------------

// H8[r][:] = fp8( rowscale_r * relu(A[r][:] @ W + bias) );  rowscale NULL -> 1.
#define RCH 32
__global__ void __launch_bounds__(256, 2) k_gemm(const uint* __restrict__ A,
                                                 const uint4* __restrict__ wfrag,
                                                 const float* __restrict__ bias,
                                                 const float* __restrict__ rowscale,
                                                 uint* __restrict__ H8, int N) {
    __shared__ uint4 sAf[4][2][64];      // [kb][rowgrp][lane], 8 KB
    __shared__ float sEp[4][16][68];     // per-wave epilogue scratch
    int t = threadIdx.x;
    int w = t >> 6;
    int lane = t & 63;
    int rowgrp = w >> 1;
    int colh = w & 1;

    bf16x8 Bf[4][4];
#pragma unroll
    for (int kb = 0; kb < 4; ++kb)
#pragma unroll
        for (int i = 0; i < 4; ++i)
            Bf[kb][i] = as_bf16x8(wfrag[(kb * 8 + colh * 4 + i) * 64 + lane]);

    float4 bb = ((const float4*)bias)[colh * 16 + (lane & 15)];

    int nchunk = (N + RCH - 1) / RCH;
    for (int ch = blockIdx.x; ch < nchunk; ch += gridDim.x) {
        int r0 = ch * RCH;
        __syncthreads();
#pragma unroll
        for (int s = 0; s < 2; ++s) {
            int i = t + s * 256;
            int kb = i >> 7;
            int rg = (i >> 6) & 1;
            int ln = i & 63;
            int gr = r0 + rg * 16 + (ln & 15);
            gr = min(gr, N - 1);
            sAf[kb][rg][ln] = ((const uint4*)(A + (size_t)gr * 64))[kb * 4 + (ln >> 4)];
        }
        __syncthreads();

        f32x4 acc[4] = {{0.f, 0.f, 0.f, 0.f}, {0.f, 0.f, 0.f, 0.f},
                        {0.f, 0.f, 0.f, 0.f}, {0.f, 0.f, 0.f, 0.f}};
#pragma unroll
        for (int kb = 0; kb < 4; ++kb) {
            bf16x8 af = as_bf16x8(sAf[kb][rowgrp][lane]);
#pragma unroll
            for (int i = 0; i < 4; ++i)
                acc[i] = __builtin_amdgcn_mfma_f32_16x16x32_bf16(af, Bf[kb][i], acc[i], 0, 0, 0);
        }

#pragma unroll
        for (int i = 0; i < 4; ++i) {
#pragma unroll
            for (int reg = 0; reg < 4; ++reg)
                sEp[w][(lane >> 4) * 4 + reg][i * 16 + (lane & 15)] = acc[i][reg];
        }
#pragma unroll
        for (int e = 0; e < 4; ++e) {
            int rr = (lane >> 4) + 4 * e;   // 0..15
            int cu = lane & 15;
            const float* sp = &sEp[w][rr][cu * 4];
            int rowg = r0 + rowgrp * 16 + rr;
            if (rowg < N) {
                float sc = rowscale ? rowscale[rowg] : 1.0f;
                float o0 = sc * fmaxf(sp[0] + bb.x, 0.f);
                float o1 = sc * fmaxf(sp[1] + bb.y, 0.f);
                float o2 = sc * fmaxf(sp[2] + bb.z, 0.f);
                float o3 = sc * fmaxf(sp[3] + bb.w, 0.f);
                H8[(size_t)rowg * 32 + colh * 16 + cu] = pack4fp8(o0, o1, o2, o3);
            }
        }
    }
}

// ---------------- pooling + classifier ----------------

// 4 blocks/graph x 128 thr = 32 uint-cols x 16 row-segments (round-11 proven).
__global__ void k_pool(const uint* __restrict__ h8, const int* __restrict__ batch,
                       float* __restrict__ gpool, float* __restrict__ gcnt, int N) {
    int gi = blockIdx.x >> 2, part = blockIdx.x & 3;
    int t = threadIdx.x;
    int ui = t & 31;
    int sub = t >> 5;
    int lo = 0, hi = N;
    while (lo < hi) { int m = (lo + hi) >> 1; if (batch[m] < gi) lo = m + 1; else hi = m; }
    int start = lo;
    lo = start; hi = N;
    while (lo < hi) { int m = (lo + hi) >> 1; if (batch[m] <= gi) lo = m + 1; else hi = m; }
    int end = lo;
    if (part == 0 && t == 0) gcnt[gi] = (float)(end - start);
    int len = end - start;
    int q = (len + 15) >> 4;
    int seg = part * 4 + sub;
    int rs = start + seg * q;
    int re = min(end, rs + q);
    float s0 = 0.f, s1 = 0.f, s2 = 0.f, s3 = 0.f;
    for (int i = rs; i < re; ++i) {
        uint qq = h8[(size_t)i * 32 + ui];
        f32x2 lo2 = fp8lo(qq), hi2 = fp8hi(qq);
        s0 += lo2.x; s1 += lo2.y; s2 += hi2.x; s3 += hi2.y;
    }
    if (re > rs) {
        float* gp = gpool + gi * HID + ui * 4;
        atomicAdd(gp + 0, s0);
        atomicAdd(gp + 1, s1);
        atomicAdd(gp + 2, s2);
        atomicAdd(gp + 3, s3);
    }
}

__global__ void k_cls(const float* __restrict__ gpool, const float* __restrict__ gcnt,
                      const float* __restrict__ Wc1, const float* __restrict__ bc1,
                      const float* __restrict__ Wc2, const float* __restrict__ bc2,
                      float* __restrict__ out) {
    int g = blockIdx.x;
    int j = threadIdx.x;  // 64
    float inv = 1.0f / fmaxf(gcnt[g], 1.0f);
    float z = bc1[j];
    for (int k = 0; k < HID; ++k) z = fmaf(gpool[g * HID + k] * inv, Wc1[k * 64 + j], z);
    z = fmaxf(z, 0.f);
    float p = z * Wc2[j];
    for (int off = 32; off; off >>= 1) p += __shfl_down(p, off);
    if (j == 0) out[g] = 1.0f / (1.0f + expf(-(p + bc2[0])));
}

// ---------------- launch ----------------

extern "C" void kernel_launch(void* const* d_in, const int* in_sizes, int n_in,
                              void* d_out, int out_size, void* d_ws, size_t ws_size,
                              hipStream_t stream) {
    const float* x     = (const float*)d_in[0];
    const int*   eidx  = (const int*)d_in[1];
    const int*   batch = (const int*)d_in[2];
    const float* W_emb = (const float*)d_in[3];
    const float* b_emb = (const float*)d_in[4];
    const float* W_gnn = (const float*)d_in[5];
    const float* b_gnn = (const float*)d_in[6];
    const float* W_c1  = (const float*)d_in[7];
    const float* b_c1  = (const float*)d_in[8];
    const float* W_c2  = (const float*)d_in[9];
    const float* b_c2  = (const float*)d_in[10];

    const int N = in_sizes[0];        // 100000
    const int E = in_sizes[1] / 2;    // 3200000
    const int G = out_size;           // 128
    const int* row = eidx;
    const int* col = eidx + E;
    const int NBUK = (N + 511) >> WSH;   // 196 coarse buckets

    char* ws = (char*)d_ws;
    auto alloc = [&](size_t bytes) -> void* {
        void* p = (void*)ws;
        ws += (bytes + 255) & ~(size_t)255;
        return p;
    };
    int*    cnt    = (int*)alloc((size_t)N * 4);
    float*  dinv   = (float*)alloc((size_t)N * 4);
    float2* pk0    = (float2*)alloc((size_t)N * 8);
    int*    bukCur = (int*)alloc(256 * 4);
    uint*   recs   = (uint*)alloc((size_t)NBUK * BUKCAP * 4);  // 19.3 MB
    int*    ebin   = (int*)alloc((size_t)N * CAP * 4);         // 38.4 MB
    float*  u      = (float*)alloc(HID * 4);
    float*  v      = (float*)alloc(HID * 4);
    uint*   G8     = (uint*)alloc((size_t)N * 32 * 4);   // fp8 (dinv-scaled / final H)
    uint*   A      = (uint*)alloc((size_t)N * 64 * 4);   // bf16 packed, 25.6 MB
    uint4*  wfrag  = (uint4*)alloc(4096 * 16);           // B-frags, 2 layers
    float*  gpool  = (float*)alloc((size_t)G * HID * 4);
    float*  gcnt   = (float*)alloc((size_t)G * 4);

    hipMemsetAsync(bukCur, 0, 256 * 4, stream);
    hipMemsetAsync(gpool, 0, (size_t)G * HID * 4, stream);

    // two-phase binning; cnt/dinv/pk0 produced by fused phase B
    k_part<<<(E + TILE - 1) / TILE, 256, 0, stream>>>(row, col, bukCur, recs, E);
    k_fbin<<<NBUK, 256, 0, stream>>>(recs, bukCur, x, cnt, ebin, dinv, pk0, N);

    // fused W-prep (u/v + MFMA B-fragments)
    k_wprep<<<17, 256, 0, stream>>>(W_emb, b_emb, W_gnn, u, v, wfrag);

    // layer 0: fused scalar-agg + h1 -> g8
    k_sagg<<<(N + 255) / 256, 256, 0, stream>>>(cnt, ebin, x, dinv, pk0, u, v, b_gnn, G8, N);

    // layers 1,2: gather-add agg + MFMA GEMM.  Layer-1 GEMM pre-scales rows
    // by dinv (output consumed by agg); layer-2 output is plain H (pooling).
    int nchunk = (N + RCH - 1) / RCH;
    int gblk = nchunk < 768 ? nchunk : 768;
    for (int l = 1; l < 3; ++l) {
        k_agg<<<(N + 3) / 4, 256, 0, stream>>>(cnt, ebin, dinv, G8, A, N);
        k_gemm<<<gblk, 256, 0, stream>>>(A, wfrag + (size_t)(l - 1) * 2048,
                                         b_gnn + (size_t)l * HID,
                                         (l == 1) ? dinv : (const float*)nullptr,
                                         G8, N);
    }

    k_pool<<<G * 4, 128, 0, stream>>>(G8, batch, gpool, gcnt, N);
    k_cls<<<G, 64, 0, stream>>>(gpool, gcnt, W_c1, b_c1, W_c2, b_c2, (float*)d_out);
}

// Round 4
// 379.969 us; speedup vs baseline: 1.0083x; 1.0083x over previous
//
#include <hip/hip_runtime.h>
#include <math.h>

#define HID 128
#define CAP 96       // per-node bucket capacity; deg ~ Poisson(32), P(>96) ~ 1e-18
#define TILE 8192    // edges per partition block
#define WSH 9        // coarse bucket = 512-node window
#define BUKCAP 24576 // per-bucket record capacity

typedef unsigned int uint;
typedef unsigned short ushort;
typedef float f32x2 __attribute__((ext_vector_type(2)));
typedef float f32x4 __attribute__((ext_vector_type(4)));
typedef uint u32x4 __attribute__((ext_vector_type(4)));    // native vec for nontemporal
typedef short bf16x8 __attribute__((ext_vector_type(8)));  // 8 bf16 in 4 VGPRs

// ---- bf16 helpers ----
__device__ inline ushort f2bf(float f) {
    uint u = __float_as_uint(f);
    return (ushort)((u + 0x7fffu + ((u >> 16) & 1u)) >> 16);
}
__device__ inline uint packbf(float a, float b) {
    return (uint)f2bf(a) | ((uint)f2bf(b) << 16);
}
__device__ inline bf16x8 as_bf16x8(uint4 u) {
    union { uint4 a; bf16x8 b; } c;
    c.a = u;
    return c.b;
}

// ---- fp8 e4m3 helpers (HW converts, RNE+sat) ----
__device__ inline f32x2 fp8lo(uint q) { return __builtin_amdgcn_cvt_pk_f32_fp8(q, false); }
__device__ inline f32x2 fp8hi(uint q) { return __builtin_amdgcn_cvt_pk_f32_fp8(q, true); }
__device__ inline uint pack4fp8(float a, float b, float c, float d) {
    int t = __builtin_amdgcn_cvt_pk_fp8_f32(a, b, 0, false);
    return (uint)__builtin_amdgcn_cvt_pk_fp8_f32(c, d, t, true);
}

// ---------------- two-phase binning (no per-edge global atomics) ----------------

// Phase A: LDS histogram over an 8192-edge tile, one global atomic per touched
// bucket, packed records written as ~41-edge runs.
__global__ void __launch_bounds__(256) k_part(const int* __restrict__ row,
                                              const int* __restrict__ col,
                                              int* __restrict__ bukCur,
                                              uint* __restrict__ recs, int E) {
    __shared__ int hist[256];
    __shared__ int hist2[256];
    __shared__ uint base[256];
    int t = threadIdx.x;
    hist[t] = 0;
    hist2[t] = 0;
    __syncthreads();
    int i0 = blockIdx.x * TILE;
    int i1 = min(E, i0 + TILE);
    for (int i = i0 + t; i < i1; i += 256) {
        int b = col[i] >> WSH;
        atomicAdd(&hist[b], 1);
    }
    __syncthreads();
    if (hist[t] > 0) base[t] = (uint)atomicAdd(&bukCur[t], hist[t]);
    __syncthreads();
    for (int i = i0 + t; i < i1; i += 256) {
        int c = col[i];
        int b = c >> WSH;
        uint p = (uint)atomicAdd(&hist2[b], 1);
        uint idx = base[b] + p;
        if (idx < BUKCAP)
            recs[(size_t)b * BUKCAP + idx] = (uint)row[i] | ((uint)(c & 511) << 17);
    }
}

// Phase B: one block per bucket; per-node cursors in LDS; ebin gets PRE-SHIFTED
// source offsets (r<<5).  Fused prep tail: dinv + pk0 from in-LDS counts.
// (round-1 single-pass version; window-sort experiment reverted, 0 effect)
__global__ void __launch_bounds__(256) k_fbin(const uint* __restrict__ recs,
                                              const int* __restrict__ bukCur,
                                              const float* __restrict__ x,
                                              int* __restrict__ cnt,
                                              int* __restrict__ ebin,
                                              float* __restrict__ dinv,
                                              float2* __restrict__ pk0, int N) {
    __shared__ int lcnt[512];
    int b = blockIdx.x;
    int t = threadIdx.x;
    lcnt[t] = 0;
    lcnt[t + 256] = 0;
    __syncthreads();
    int n = min(bukCur[b], BUKCAP);
    const uint* rp = recs + (size_t)b * BUKCAP;
    int cbase = b << WSH;
    for (int j = t; j < n; j += 256) {
        uint u = rp[j];
        int r = (int)(u & 0x1FFFFu);
        int cl = (int)(u >> 17);
        int p = atomicAdd(&lcnt[cl], 1);
        if (p < CAP) ebin[(size_t)(cbase + cl) * CAP + p] = r << 5;
    }
    __syncthreads();
    int c0 = cbase + t;
    if (c0 < N) {
        cnt[c0] = lcnt[t];
        float d = rsqrtf((float)lcnt[t] + 1.0f);  // +1 self-loop
        dinv[c0] = d;
        pk0[c0] = make_float2(d, d * x[c0]);
    }
    int c1 = cbase + t + 256;
    if (c1 < N) {
        cnt[c1] = lcnt[t + 256];
        float d = rsqrtf((float)lcnt[t + 256] + 1.0f);
        dinv[c1] = d;
        pk0[c1] = make_float2(d, d * x[c1]);
    }
}

// ---------------- fused W-prep: u/v (layer-0 analytic) + B-fragments ----------------

__global__ void k_wprep(const float* __restrict__ W_emb, const float* __restrict__ b_emb,
                        const float* __restrict__ W_gnn,
                        float* __restrict__ u, float* __restrict__ v,
                        uint4* __restrict__ wfrag) {
    int b = blockIdx.x;
    int t = threadIdx.x;
    if (b < 16) {
        int gid = b * 256 + t;   // 0..4095
        int l = gid >> 11;
        int rem = gid & 2047;
        int kb = rem >> 9;
        int nt = (rem >> 6) & 7;
        int lane = rem & 63;
        int k0 = kb * 32 + (lane >> 4) * 8;
        int n = nt * 16 + (lane & 15);
        const float* Wp = W_gnn + (size_t)(l + 1) * HID * HID;
        uint4 o;
        o.x = packbf(Wp[(k0 + 0) * HID + n], Wp[(k0 + 1) * HID + n]);
        o.y = packbf(Wp[(k0 + 2) * HID + n], Wp[(k0 + 3) * HID + n]);
        o.z = packbf(Wp[(k0 + 4) * HID + n], Wp[(k0 + 5) * HID + n]);
        o.w = packbf(Wp[(k0 + 6) * HID + n], Wp[(k0 + 7) * HID + n]);
        wfrag[gid] = o;
    } else if (t < HID) {
        float su = 0.f, sv = 0.f;
        for (int k = 0; k < HID; ++k) {
            float w = W_gnn[k * HID + t];
            su = fmaf(W_emb[k], w, su);
            sv = fmaf(b_emb[k], w, sv);
        }
        u[t] = su;
        v[t] = sv;
    }
}

// ---------------- layer 0: fused scalar-agg + h1 (g8 output) ----------------

__global__ void __launch_bounds__(256) k_sagg(const int* __restrict__ cnt,
                                              const int* __restrict__ ebin,
                                              const float* __restrict__ x,
                                              const float* __restrict__ dinv,
                                              const float2* __restrict__ pk0,
                                              const float* __restrict__ u,
                                              const float* __restrict__ v,
                                              const float* __restrict__ b0,
                                              uint* __restrict__ g8, int N) {
    __shared__ float sS0[256], sS1[256], sDc[256];
    int t = threadIdx.x;
    int c0 = blockIdx.x * 256;
    int c = c0 + t;
    if (c < N) {
        float dc = dinv[c];
        float A = 0.f, B = 0.f;
        int n = min(cnt[c], CAP);
        const int* bp = ebin + (size_t)c * CAP;
        int k = 0;
        for (; k + 4 <= n; k += 4) {
            float2 p0 = pk0[bp[k] >> 5], p1 = pk0[bp[k + 1] >> 5];
            float2 p2 = pk0[bp[k + 2] >> 5], p3 = pk0[bp[k + 3] >> 5];
            A += (p0.x + p1.x) + (p2.x + p3.x);
            B += (p0.y + p1.y) + (p2.y + p3.y);
        }
        for (; k < n; ++k) {
            float2 p = pk0[bp[k] >> 5];
            A += p.x;
            B += p.y;
        }
        float d2 = dc * dc;
        sS0[t] = fmaf(dc, A, d2);
        sS1[t] = fmaf(dc, B, d2 * x[c]);
        sDc[t] = dc;
    }
    __syncthreads();
    int nloc = min(256, N - c0);
    int total = nloc * 32;
    for (int gid = t; gid < total; gid += 256) {
        int lc = gid >> 5;
        int j = (gid & 31) * 4;
        float t1 = sS1[lc], t0 = sS0[lc], dc = sDc[lc];
        float v0 = fmaxf(fmaf(t1, u[j + 0], fmaf(t0, v[j + 0], b0[j + 0])), 0.f);
        float v1 = fmaxf(fmaf(t1, u[j + 1], fmaf(t0, v[j + 1], b0[j + 1])), 0.f);
        float v2 = fmaxf(fmaf(t1, u[j + 2], fmaf(t0, v[j + 2], b0[j + 2])), 0.f);
        float v3 = fmaxf(fmaf(t1, u[j + 3], fmaf(t0, v[j + 3], b0[j + 3])), 0.f);
        g8[(size_t)(c0 + lc) * 32 + (gid & 31)] = pack4fp8(dc * v0, dc * v1, dc * v2, dc * v3);
    }
}

// ---------------- aggregate: pure gather-add of pre-scaled g8 ----------------
// v3: 2 nodes per wave + 2-deep software pipeline.  Per iteration:
// compute A_k -> issue A_{k+2} -> compute B_k -> issue B_{k+2} -> compute
// A_{k+1} -> ... so each compute has ~2 stages of issued work covering its
// load latency and 12 load-instrs stay outstanding per wave (was 4, serial).
// Blocks padded to 16 edges with clamped offsets + zeroed contributions
// (wave-uniform branches).  ebin reads + a stores are non-temporal so the
// streaming traffic (38 MB/dispatch) stops evicting the g8 gather table.

#define ISSUE(ro0_, ro1_, tX, k, b0, b1, b2, b3)                          \
    {                                                                     \
        int ro_ = ((k) < 4) ? (ro0_) : (ro1_);                            \
        int jo_ = ((k) & 3) * 16;                                         \
        int l0_ = jo_ + qg, l1_ = jo_ + 4 + qg;                           \
        int l2_ = jo_ + 8 + qg, l3_ = jo_ + 12 + qg;                      \
        if ((tX) < ((k) + 1) * 16) {                                      \
            int tr_ = (tX) - 1 - (((k) >= 4) ? 64 : 0);                   \
            l0_ = min(l0_, tr_); l1_ = min(l1_, tr_);                     \
            l2_ = min(l2_, tr_); l3_ = min(l3_, tr_);                     \
        }                                                                 \
        b0 = *(const uint2*)(gq + __shfl(ro_, l0_));                      \
        b1 = *(const uint2*)(gq + __shfl(ro_, l1_));                      \
        b2 = *(const uint2*)(gq + __shfl(ro_, l2_));                      \
        b3 = *(const uint2*)(gq + __shfl(ro_, l3_));                      \
    }

#define ACC1(q_, x0, x1, x2, x3)                                          \
    { x0 += fp8lo(q_.x); x1 += fp8hi(q_.x); x2 += fp8lo(q_.y); x3 += fp8hi(q_.y); }

#define COMPUTE(tX, k, b0, b1, b2, b3, x0, x1, x2, x3)                    \
    {                                                                     \
        if ((tX) < ((k) + 1) * 16) {                                      \
            int e_ = (k) * 16 + qg;                                       \
            if (e_ >= (tX))      { b0.x = 0u; b0.y = 0u; }                \
            if (e_ + 4 >= (tX))  { b1.x = 0u; b1.y = 0u; }                \
            if (e_ + 8 >= (tX))  { b2.x = 0u; b2.y = 0u; }                \
            if (e_ + 12 >= (tX)) { b3.x = 0u; b3.y = 0u; }                \
        }                                                                 \
        ACC1(b0, x0, x1, x2, x3); ACC1(b1, x0, x1, x2, x3);               \
        ACC1(b2, x0, x1, x2, x3); ACC1(b3, x0, x1, x2, x3);               \
    }

__global__ void __launch_bounds__(256) k_agg(const int* __restrict__ cnt,
                                             const int* __restrict__ ebin,
                                             const float* __restrict__ dinv,
                                             const uint* __restrict__ g8,
                                             uint* __restrict__ a, int N) {
    int pair = (blockIdx.x * 256 + threadIdx.x) >> 6;
    int cA = pair * 2;
    if (cA >= N) return;
    int cB = cA + 1;
    bool hasB = (cB < N);
    int lane = threadIdx.x & 63;
    int ql = lane & 15;
    int qg = lane >> 4;
    const uint* __restrict__ gq = g8 + ql * 2;   // this lane's 8B column slice

    int tA = min(cnt[cA], CAP) + 1;               // + self row
    int tB = hasB ? (min(cnt[cB], CAP) + 1) : 0;
    const int* __restrict__ bpA = ebin + (size_t)cA * CAP - 1;  // bp[gi], gi>=1
    const int* __restrict__ bpB = ebin + (size_t)cB * CAP - 1;

    // chunk offset registers (clamped, non-temporal; gi==0 -> self row)
    int iA = min(lane, tA - 1);
    int lvA = __builtin_nontemporal_load(bpA + max(iA, 1));
    int roA0 = (iA == 0) ? (cA << 5) : lvA;
    int roA1 = 0;
    if (tA > 64) roA1 = __builtin_nontemporal_load(bpA + min(64 + lane, tA - 1));
    int roB0 = 0, roB1 = 0;
    if (hasB) {
        int iB = min(lane, tB - 1);
        int lvB = __builtin_nontemporal_load(bpB + max(iB, 1));
        roB0 = (iB == 0) ? (cB << 5) : lvB;
        if (tB > 64) roB1 = __builtin_nontemporal_load(bpB + min(64 + lane, tB - 1));
    }

    int nbA = (tA + 15) >> 4;
    int nbB = (tB + 15) >> 4;   // 0 when !hasB
    int nb = max(nbA, nbB);

    f32x2 aA0 = {0.f, 0.f}, aA1 = {0.f, 0.f}, aA2 = {0.f, 0.f}, aA3 = {0.f, 0.f};
    f32x2 aB0 = {0.f, 0.f}, aB1 = {0.f, 0.f}, aB2 = {0.f, 0.f}, aB3 = {0.f, 0.f};
    uint2 qA00, qA01, qA02, qA03, qA10, qA11, qA12, qA13;
    uint2 qB00, qB01, qB02, qB03, qB10, qB11, qB12, qB13;

    // prologue: 2-deep prefetch for both nodes
    ISSUE(roA0, roA1, tA, 0, qA00, qA01, qA02, qA03);
    if (0 < nbB) ISSUE(roB0, roB1, tB, 0, qB00, qB01, qB02, qB03);
    if (1 < nbA) ISSUE(roA0, roA1, tA, 1, qA10, qA11, qA12, qA13);
    if (1 < nbB) ISSUE(roB0, roB1, tB, 1, qB10, qB11, qB12, qB13);

    int k = 0;
    for (; k + 1 < nb; k += 2) {
        if (k < nbA) COMPUTE(tA, k, qA00, qA01, qA02, qA03, aA0, aA1, aA2, aA3);
        if (k + 2 < nbA) ISSUE(roA0, roA1, tA, k + 2, qA00, qA01, qA02, qA03);
        if (k < nbB) COMPUTE(tB, k, qB00, qB01, qB02, qB03, aB0, aB1, aB2, aB3);
        if (k + 2 < nbB) ISSUE(roB0, roB1, tB, k + 2, qB00, qB01, qB02, qB03);
        if (k + 1 < nbA) COMPUTE(tA, k + 1, qA10, qA11, qA12, qA13, aA0, aA1, aA2, aA3);
        if (k + 3 < nbA) ISSUE(roA0, roA1, tA, k + 3, qA10, qA11, qA12, qA13);
        if (k + 1 < nbB) COMPUTE(tB, k + 1, qB10, qB11, qB12, qB13, aB0, aB1, aB2, aB3);
        if (k + 3 < nbB) ISSUE(roB0, roB1, tB, k + 3, qB10, qB11, qB12, qB13);
    }
    if (k < nb) {
        if (k < nbA) COMPUTE(tA, k, qA00, qA01, qA02, qA03, aA0, aA1, aA2, aA3);
        if (k < nbB) COMPUTE(tB, k, qB00, qB01, qB02, qB03, aB0, aB1, aB2, aB3);
    }

    // butterfly reduce (all lanes end with full sums for both nodes)
    float rA0 = aA0.x, rA1 = aA0.y, rA2 = aA1.x, rA3 = aA1.y;
    float rA4 = aA2.x, rA5 = aA2.y, rA6 = aA3.x, rA7 = aA3.y;
    float rB0 = aB0.x, rB1 = aB0.y, rB2 = aB1.x, rB3 = aB1.y;
    float rB4 = aB2.x, rB5 = aB2.y, rB6 = aB3.x, rB7 = aB3.y;
#pragma unroll
    for (int m = 16; m <= 32; m <<= 1) {
        rA0 += __shfl_xor(rA0, m); rA1 += __shfl_xor(rA1, m);
        rA2 += __shfl_xor(rA2, m); rA3 += __shfl_xor(rA3, m);
        rA4 += __shfl_xor(rA4, m); rA5 += __shfl_xor(rA5, m);
        rA6 += __shfl_xor(rA6, m); rA7 += __shfl_xor(rA7, m);
        rB0 += __shfl_xor(rB0, m); rB1 += __shfl_xor(rB1, m);
        rB2 += __shfl_xor(rB2, m); rB3 += __shfl_xor(rB3, m);
        rB4 += __shfl_xor(rB4, m); rB5 += __shfl_xor(rB5, m);
        rB6 += __shfl_xor(rB6, m); rB7 += __shfl_xor(rB7, m);
    }
    if (qg == 0) {
        float dc = dinv[cA];
        u32x4 o;
        o.x = packbf(dc * rA0, dc * rA1);
        o.y = packbf(dc * rA2, dc * rA3);
        o.z = packbf(dc * rA4, dc * rA5);
        o.w = packbf(dc * rA6, dc * rA7);
        __builtin_nontemporal_store(o, (u32x4*)(a + (size_t)cA * 64) + ql);
    } else if (qg == 1 && hasB) {
        float dc = dinv[cB];
        u32x4 o;
        o.x = packbf(dc * rB0, dc * rB1);
        o.y = packbf(dc * rB2, dc * rB3);
        o.z = packbf(dc * rB4, dc * rB5);
        o.w = packbf(dc * rB6, dc * rB7);
        __builtin_nontemporal_store(o, (u32x4*)(a + (size_t)cB * 64) + ql);
    }
}

// ---------------- MFMA GEMM ----------------

// H8[r][:] = fp8( rowscale_r * relu(A[r][:] @ W + bias) );  rowscale NULL -> 1.
#define RCH 32
__global__ void __launch_bounds__(256, 2) k_gemm(const uint* __restrict__ A,
                                                 const uint4* __restrict__ wfrag,
                                                 const float* __restrict__ bias,
                                                 const float* __restrict__ rowscale,
                                                 uint* __restrict__ H8, int N) {
    __shared__ uint4 sAf[4][2][64];      // [kb][rowgrp][lane], 8 KB
    __shared__ float sEp[4][16][68];     // per-wave epilogue scratch
    int t = threadIdx.x;
    int w = t >> 6;
    int lane = t & 63;
    int rowgrp = w >> 1;
    int colh = w & 1;

    bf16x8 Bf[4][4];
#pragma unroll
    for (int kb = 0; kb < 4; ++kb)
#pragma unroll
        for (int i = 0; i < 4; ++i)
            Bf[kb][i] = as_bf16x8(wfrag[(kb * 8 + colh * 4 + i) * 64 + lane]);

    float4 bb = ((const float4*)bias)[colh * 16 + (lane & 15)];

    int nchunk = (N + RCH - 1) / RCH;
    for (int ch = blockIdx.x; ch < nchunk; ch += gridDim.x) {
        int r0 = ch * RCH;
        __syncthreads();
#pragma unroll
        for (int s = 0; s < 2; ++s) {
            int i = t + s * 256;
            int kb = i >> 7;
            int rg = (i >> 6) & 1;
            int ln = i & 63;
            int gr = r0 + rg * 16 + (ln & 15);
            gr = min(gr, N - 1);
            sAf[kb][rg][ln] = ((const uint4*)(A + (size_t)gr * 64))[kb * 4 + (ln >> 4)];
        }
        __syncthreads();

        f32x4 acc[4] = {{0.f, 0.f, 0.f, 0.f}, {0.f, 0.f, 0.f, 0.f},
                        {0.f, 0.f, 0.f, 0.f}, {0.f, 0.f, 0.f, 0.f}};
#pragma unroll
        for (int kb = 0; kb < 4; ++kb) {
            bf16x8 af = as_bf16x8(sAf[kb][rowgrp][lane]);
#pragma unroll
            for (int i = 0; i < 4; ++i)
                acc[i] = __builtin_amdgcn_mfma_f32_16x16x32_bf16(af, Bf[kb][i], acc[i], 0, 0, 0);
        }

#pragma unroll
        for (int i = 0; i < 4; ++i) {
#pragma unroll
            for (int reg = 0; reg < 4; ++reg)
                sEp[w][(lane >> 4) * 4 + reg][i * 16 + (lane & 15)] = acc[i][reg];
        }
#pragma unroll
        for (int e = 0; e < 4; ++e) {
            int rr = (lane >> 4) + 4 * e;   // 0..15
            int cu = lane & 15;
            const float* sp = &sEp[w][rr][cu * 4];
            int rowg = r0 + rowgrp * 16 + rr;
            if (rowg < N) {
                float sc = rowscale ? rowscale[rowg] : 1.0f;
                float o0 = sc * fmaxf(sp[0] + bb.x, 0.f);
                float o1 = sc * fmaxf(sp[1] + bb.y, 0.f);
                float o2 = sc * fmaxf(sp[2] + bb.z, 0.f);
                float o3 = sc * fmaxf(sp[3] + bb.w, 0.f);
                H8[(size_t)rowg * 32 + colh * 16 + cu] = pack4fp8(o0, o1, o2, o3);
            }
        }
    }
}

// ---------------- pooling + classifier ----------------

// 4 blocks/graph x 128 thr = 32 uint-cols x 16 row-segments (round-11 proven).
__global__ void k_pool(const uint* __restrict__ h8, const int* __restrict__ batch,
                       float* __restrict__ gpool, float* __restrict__ gcnt, int N) {
    int gi = blockIdx.x >> 2, part = blockIdx.x & 3;
    int t = threadIdx.x;
    int ui = t & 31;
    int sub = t >> 5;
    int lo = 0, hi = N;
    while (lo < hi) { int m = (lo + hi) >> 1; if (batch[m] < gi) lo = m + 1; else hi = m; }
    int start = lo;
    lo = start; hi = N;
    while (lo < hi) { int m = (lo + hi) >> 1; if (batch[m] <= gi) lo = m + 1; else hi = m; }
    int end = lo;
    if (part == 0 && t == 0) gcnt[gi] = (float)(end - start);
    int len = end - start;
    int q = (len + 15) >> 4;
    int seg = part * 4 + sub;
    int rs = start + seg * q;
    int re = min(end, rs + q);
    float s0 = 0.f, s1 = 0.f, s2 = 0.f, s3 = 0.f;
    for (int i = rs; i < re; ++i) {
        uint qq = h8[(size_t)i * 32 + ui];
        f32x2 lo2 = fp8lo(qq), hi2 = fp8hi(qq);
        s0 += lo2.x; s1 += lo2.y; s2 += hi2.x; s3 += hi2.y;
    }
    if (re > rs) {
        float* gp = gpool + gi * HID + ui * 4;
        atomicAdd(gp + 0, s0);
        atomicAdd(gp + 1, s1);
        atomicAdd(gp + 2, s2);
        atomicAdd(gp + 3, s3);
    }
}

__global__ void k_cls(const float* __restrict__ gpool, const float* __restrict__ gcnt,
                      const float* __restrict__ Wc1, const float* __restrict__ bc1,
                      const float* __restrict__ Wc2, const float* __restrict__ bc2,
                      float* __restrict__ out) {
    int g = blockIdx.x;
    int j = threadIdx.x;  // 64
    float inv = 1.0f / fmaxf(gcnt[g], 1.0f);
    float z = bc1[j];
    for (int k = 0; k < HID; ++k) z = fmaf(gpool[g * HID + k] * inv, Wc1[k * 64 + j], z);
    z = fmaxf(z, 0.f);
    float p = z * Wc2[j];
    for (int off = 32; off; off >>= 1) p += __shfl_down(p, off);
    if (j == 0) out[g] = 1.0f / (1.0f + expf(-(p + bc2[0])));
}

// ---------------- launch ----------------

extern "C" void kernel_launch(void* const* d_in, const int* in_sizes, int n_in,
                              void* d_out, int out_size, void* d_ws, size_t ws_size,
                              hipStream_t stream) {
    const float* x     = (const float*)d_in[0];
    const int*   eidx  = (const int*)d_in[1];
    const int*   batch = (const int*)d_in[2];
    const float* W_emb = (const float*)d_in[3];
    const float* b_emb = (const float*)d_in[4];
    const float* W_gnn = (const float*)d_in[5];
    const float* b_gnn = (const float*)d_in[6];
    const float* W_c1  = (const float*)d_in[7];
    const float* b_c1  = (const float*)d_in[8];
    const float* W_c2  = (const float*)d_in[9];
    const float* b_c2  = (const float*)d_in[10];

    const int N = in_sizes[0];        // 100000
    const int E = in_sizes[1] / 2;    // 3200000
    const int G = out_size;           // 128
    const int* row = eidx;
    const int* col = eidx + E;
    const int NBUK = (N + 511) >> WSH;   // 196 coarse buckets

    char* ws = (char*)d_ws;
    auto alloc = [&](size_t bytes) -> void* {
        void* p = (void*)ws;
        ws += (bytes + 255) & ~(size_t)255;
        return p;
    };
    int*    cnt    = (int*)alloc((size_t)N * 4);
    float*  dinv   = (float*)alloc((size_t)N * 4);
    float2* pk0    = (float2*)alloc((size_t)N * 8);
    int*    bukCur = (int*)alloc(256 * 4);
    uint*   recs   = (uint*)alloc((size_t)NBUK * BUKCAP * 4);  // 19.3 MB
    int*    ebin   = (int*)alloc((size_t)N * CAP * 4);         // 38.4 MB
    float*  u      = (float*)alloc(HID * 4);
    float*  v      = (float*)alloc(HID * 4);
    uint*   G8     = (uint*)alloc((size_t)N * 32 * 4);   // fp8 (dinv-scaled / final H)
    uint*   A      = (uint*)alloc((size_t)N * 64 * 4);   // bf16 packed, 25.6 MB
    uint4*  wfrag  = (uint4*)alloc(4096 * 16);           // B-frags, 2 layers
    float*  gpool  = (float*)alloc((size_t)G * HID * 4);
    float*  gcnt   = (float*)alloc((size_t)G * 4);

    hipMemsetAsync(bukCur, 0, 256 * 4, stream);
    hipMemsetAsync(gpool, 0, (size_t)G * HID * 4, stream);

    // two-phase binning; cnt/dinv/pk0 produced by fused phase B
    k_part<<<(E + TILE - 1) / TILE, 256, 0, stream>>>(row, col, bukCur, recs, E);
    k_fbin<<<NBUK, 256, 0, stream>>>(recs, bukCur, x, cnt, ebin, dinv, pk0, N);

    // fused W-prep (u/v + MFMA B-fragments)
    k_wprep<<<17, 256, 0, stream>>>(W_emb, b_emb, W_gnn, u, v, wfrag);

    // layer 0: fused scalar-agg + h1 -> g8
    k_sagg<<<(N + 255) / 256, 256, 0, stream>>>(cnt, ebin, x, dinv, pk0, u, v, b_gnn, G8, N);

    // layers 1,2: gather-add agg + MFMA GEMM.  Layer-1 GEMM pre-scales rows
    // by dinv (output consumed by agg); layer-2 output is plain H (pooling).
    int nchunk = (N + RCH - 1) / RCH;
    int gblk = nchunk < 768 ? nchunk : 768;
    int npair = (N + 1) / 2;                      // 2 nodes per wave
    for (int l = 1; l < 3; ++l) {
        k_agg<<<(npair + 3) / 4, 256, 0, stream>>>(cnt, ebin, dinv, G8, A, N);
        k_gemm<<<gblk, 256, 0, stream>>>(A, wfrag + (size_t)(l - 1) * 2048,
                                         b_gnn + (size_t)l * HID,
                                         (l == 1) ? dinv : (const float*)nullptr,
                                         G8, N);
    }

    k_pool<<<G * 4, 128, 0, stream>>>(G8, batch, gpool, gcnt, N);
    k_cls<<<G, 64, 0, stream>>>(gpool, gcnt, W_c1, b_c1, W_c2, b_c2, (float*)d_out);
}

// Round 6
// 372.814 us; speedup vs baseline: 1.0277x; 1.0192x over previous
//
#include <hip/hip_runtime.h>
#include <math.h>

#define HID 128
#define CAP 96       // per-node bucket capacity; deg ~ Poisson(32), P(>96) ~ 1e-18
#define TILE 8192    // edges per partition block
#define WSH 9        // coarse bucket = 512-node window
#define BUKCAP 24576 // per-bucket record capacity

typedef unsigned int uint;
typedef unsigned short ushort;
typedef float f32x2 __attribute__((ext_vector_type(2)));
typedef float f32x4 __attribute__((ext_vector_type(4)));
typedef short bf16x8 __attribute__((ext_vector_type(8)));  // 8 bf16 in 4 VGPRs

// ---- bf16 helpers ----
__device__ inline ushort f2bf(float f) {
    uint u = __float_as_uint(f);
    return (ushort)((u + 0x7fffu + ((u >> 16) & 1u)) >> 16);
}
__device__ inline uint packbf(float a, float b) {
    return (uint)f2bf(a) | ((uint)f2bf(b) << 16);
}

// ---- fp8 e4m3 helpers (HW converts, RNE+sat) ----
__device__ inline f32x2 fp8lo(uint q) { return __builtin_amdgcn_cvt_pk_f32_fp8(q, false); }
__device__ inline f32x2 fp8hi(uint q) { return __builtin_amdgcn_cvt_pk_f32_fp8(q, true); }
__device__ inline uint pack4fp8(float a, float b, float c, float d) {
    int t = __builtin_amdgcn_cvt_pk_fp8_f32(a, b, 0, false);
    return (uint)__builtin_amdgcn_cvt_pk_fp8_f32(c, d, t, true);
}
__device__ inline long long as_i64(uint2 u) {
    union { uint2 a; long long b; } c;
    c.a = u;
    return c.b;
}

// ---------------- two-phase binning (no per-edge global atomics) ----------------

// Phase A: LDS histogram over an 8192-edge tile, one global atomic per touched
// bucket, packed records written as ~41-edge runs.
__global__ void __launch_bounds__(256) k_part(const int* __restrict__ row,
                                              const int* __restrict__ col,
                                              int* __restrict__ bukCur,
                                              uint* __restrict__ recs, int E) {
    __shared__ int hist[256];
    __shared__ int hist2[256];
    __shared__ uint base[256];
    int t = threadIdx.x;
    hist[t] = 0;
    hist2[t] = 0;
    __syncthreads();
    int i0 = blockIdx.x * TILE;
    int i1 = min(E, i0 + TILE);
    for (int i = i0 + t; i < i1; i += 256) {
        int b = col[i] >> WSH;
        atomicAdd(&hist[b], 1);
    }
    __syncthreads();
    if (hist[t] > 0) base[t] = (uint)atomicAdd(&bukCur[t], hist[t]);
    __syncthreads();
    for (int i = i0 + t; i < i1; i += 256) {
        int c = col[i];
        int b = c >> WSH;
        uint p = (uint)atomicAdd(&hist2[b], 1);
        uint idx = base[b] + p;
        if (idx < BUKCAP)
            recs[(size_t)b * BUKCAP + idx] = (uint)row[i] | ((uint)(c & 511) << 17);
    }
}

// Phase B: one block per bucket; per-node cursors in LDS; ebin gets PRE-SHIFTED
// source offsets (r<<5).  Fused prep tail: dinv + pk0 from in-LDS counts.
__global__ void __launch_bounds__(256) k_fbin(const uint* __restrict__ recs,
                                              const int* __restrict__ bukCur,
                                              const float* __restrict__ x,
                                              int* __restrict__ cnt,
                                              int* __restrict__ ebin,
                                              float* __restrict__ dinv,
                                              float2* __restrict__ pk0, int N) {
    __shared__ int lcnt[512];
    int b = blockIdx.x;
    int t = threadIdx.x;
    lcnt[t] = 0;
    lcnt[t + 256] = 0;
    __syncthreads();
    int n = min(bukCur[b], BUKCAP);
    const uint* rp = recs + (size_t)b * BUKCAP;
    int cbase = b << WSH;
    for (int j = t; j < n; j += 256) {
        uint u = rp[j];
        int r = (int)(u & 0x1FFFFu);
        int cl = (int)(u >> 17);
        int p = atomicAdd(&lcnt[cl], 1);
        if (p < CAP) ebin[(size_t)(cbase + cl) * CAP + p] = r << 5;
    }
    __syncthreads();
    int c0 = cbase + t;
    if (c0 < N) {
        cnt[c0] = lcnt[t];
        float d = rsqrtf((float)lcnt[t] + 1.0f);  // +1 self-loop
        dinv[c0] = d;
        pk0[c0] = make_float2(d, d * x[c0]);
    }
    int c1 = cbase + t + 256;
    if (c1 < N) {
        cnt[c1] = lcnt[t + 256];
        float d = rsqrtf((float)lcnt[t + 256] + 1.0f);
        dinv[c1] = d;
        pk0[c1] = make_float2(d, d * x[c1]);
    }
}

// ---------------- fused W-prep: u/v (layer-0 analytic) + fp8 B-fragments ----------------
// wfrag now fp8 e4m3: uint2 per (frag,lane); k-order = bytes 0..7 ascending,
// matching the A-fragment byte order (dot product invariant to shared k-perm).

__global__ void k_wprep(const float* __restrict__ W_emb, const float* __restrict__ b_emb,
                        const float* __restrict__ W_gnn,
                        float* __restrict__ u, float* __restrict__ v,
                        uint2* __restrict__ wfrag) {
    int b = blockIdx.x;
    int t = threadIdx.x;
    if (b < 16) {
        int gid = b * 256 + t;   // 0..4095
        int l = gid >> 11;
        int rem = gid & 2047;
        int kb = rem >> 9;
        int nt = (rem >> 6) & 7;
        int lane = rem & 63;
        int k0 = kb * 32 + (lane >> 4) * 8;
        int n = nt * 16 + (lane & 15);
        const float* Wp = W_gnn + (size_t)(l + 1) * HID * HID;
        uint2 o;
        o.x = pack4fp8(Wp[(k0 + 0) * HID + n], Wp[(k0 + 1) * HID + n],
                       Wp[(k0 + 2) * HID + n], Wp[(k0 + 3) * HID + n]);
        o.y = pack4fp8(Wp[(k0 + 4) * HID + n], Wp[(k0 + 5) * HID + n],
                       Wp[(k0 + 6) * HID + n], Wp[(k0 + 7) * HID + n]);
        wfrag[gid] = o;
    } else if (t < HID) {
        float su = 0.f, sv = 0.f;
        for (int k = 0; k < HID; ++k) {
            float w = W_gnn[k * HID + t];
            su = fmaf(W_emb[k], w, su);
            sv = fmaf(b_emb[k], w, sv);
        }
        u[t] = su;
        v[t] = sv;
    }
}

// ---------------- layer 0: fused scalar-agg + h1 (g8 output) ----------------

__global__ void __launch_bounds__(256) k_sagg(const int* __restrict__ cnt,
                                              const int* __restrict__ ebin,
                                              const float* __restrict__ x,
                                              const float* __restrict__ dinv,
                                              const float2* __restrict__ pk0,
                                              const float* __restrict__ u,
                                              const float* __restrict__ v,
                                              const float* __restrict__ b0,
                                              uint* __restrict__ g8, int N) {
    __shared__ float sS0[256], sS1[256], sDc[256];
    int t = threadIdx.x;
    int c0 = blockIdx.x * 256;
    int c = c0 + t;
    if (c < N) {
        float dc = dinv[c];
        float A = 0.f, B = 0.f;
        int n = min(cnt[c], CAP);
        const int* bp = ebin + (size_t)c * CAP;
        int k = 0;
        for (; k + 4 <= n; k += 4) {
            float2 p0 = pk0[bp[k] >> 5], p1 = pk0[bp[k + 1] >> 5];
            float2 p2 = pk0[bp[k + 2] >> 5], p3 = pk0[bp[k + 3] >> 5];
            A += (p0.x + p1.x) + (p2.x + p3.x);
            B += (p0.y + p1.y) + (p2.y + p3.y);
        }
        for (; k < n; ++k) {
            float2 p = pk0[bp[k] >> 5];
            A += p.x;
            B += p.y;
        }
        float d2 = dc * dc;
        sS0[t] = fmaf(dc, A, d2);
        sS1[t] = fmaf(dc, B, d2 * x[c]);
        sDc[t] = dc;
    }
    __syncthreads();
    int nloc = min(256, N - c0);
    int total = nloc * 32;
    for (int gid = t; gid < total; gid += 256) {
        int lc = gid >> 5;
        int j = (gid & 31) * 4;
        float t1 = sS1[lc], t0 = sS0[lc], dc = sDc[lc];
        float v0 = fmaxf(fmaf(t1, u[j + 0], fmaf(t0, v[j + 0], b0[j + 0])), 0.f);
        float v1 = fmaxf(fmaf(t1, u[j + 1], fmaf(t0, v[j + 1], b0[j + 1])), 0.f);
        float v2 = fmaxf(fmaf(t1, u[j + 2], fmaf(t0, v[j + 2], b0[j + 2])), 0.f);
        float v3 = fmaxf(fmaf(t1, u[j + 3], fmaf(t0, v[j + 3], b0[j + 3])), 0.f);
        g8[(size_t)(c0 + lc) * 32 + (gid & 31)] = pack4fp8(dc * v0, dc * v1, dc * v2, dc * v3);
    }
}

// ---------------- aggregate: pure gather-add of pre-scaled g8 ----------------
// round-1 proven structure (quarter-wave per row, 16 lanes x dwordx2).
// v5 change: epilogue packs A as fp8 e4m3 (8 B/lane, row = 128 B) -> halves
// the A write traffic and the GEMM's read traffic.

__global__ void __launch_bounds__(256) k_agg(const int* __restrict__ cnt,
                                             const int* __restrict__ ebin,
                                             const float* __restrict__ dinv,
                                             const uint* __restrict__ g8,
                                             uint* __restrict__ a, int N) {
    int wave = (blockIdx.x * 256 + threadIdx.x) >> 6;
    if (wave >= N) return;
    int lane = threadIdx.x & 63;
    int c = wave;
    int ql = lane & 15;
    int qg = lane >> 4;
    const uint* __restrict__ gq = g8 + ql * 2;   // this lane's 8B column slice

    f32x2 a0 = {0.f, 0.f}, a1 = {0.f, 0.f}, a2 = {0.f, 0.f}, a3 = {0.f, 0.f};

    int n = min(cnt[c], CAP);
    int total = n + 1;                                        // + self row
    const int* __restrict__ bp = ebin + (size_t)c * CAP - 1;  // bp[gi], gi>=1

    for (int base = 0; base < total; base += 64) {
        int cw = min(total - base, 64);
        int gi = base + lane;
        int ro = 0;
        if (lane < cw) ro = (gi == 0) ? (c << 5) : bp[gi];
        int j = 0;
        for (; j + 16 <= cw; j += 16) {
            int o0 = __shfl(ro, j + qg);
            int o1 = __shfl(ro, j + 4 + qg);
            int o2 = __shfl(ro, j + 8 + qg);
            int o3 = __shfl(ro, j + 12 + qg);
            uint2 q0 = *(const uint2*)(gq + o0);
            uint2 q1 = *(const uint2*)(gq + o1);
            uint2 q2 = *(const uint2*)(gq + o2);
            uint2 q3 = *(const uint2*)(gq + o3);
            a0 += fp8lo(q0.x); a1 += fp8hi(q0.x); a2 += fp8lo(q0.y); a3 += fp8hi(q0.y);
            a0 += fp8lo(q1.x); a1 += fp8hi(q1.x); a2 += fp8lo(q1.y); a3 += fp8hi(q1.y);
            a0 += fp8lo(q2.x); a1 += fp8hi(q2.x); a2 += fp8lo(q2.y); a3 += fp8hi(q2.y);
            a0 += fp8lo(q3.x); a1 += fp8hi(q3.x); a2 += fp8lo(q3.y); a3 += fp8hi(q3.y);
        }
        for (; j + 4 <= cw; j += 4) {
            int o0 = __shfl(ro, j + qg);
            uint2 q0 = *(const uint2*)(gq + o0);
            a0 += fp8lo(q0.x); a1 += fp8hi(q0.x); a2 += fp8lo(q0.y); a3 += fp8hi(q0.y);
        }
        if (j < cw) {   // 1..3 leftover edges; clamped lanes re-read a hot row, zeroed
            int e = j + qg;
            int o0 = __shfl(ro, min(e, cw - 1));
            uint2 q0 = *(const uint2*)(gq + o0);
            if (e >= cw) { q0.x = 0u; q0.y = 0u; }
            a0 += fp8lo(q0.x); a1 += fp8hi(q0.x); a2 += fp8lo(q0.y); a3 += fp8hi(q0.y);
        }
    }

    // reduce the 4 quarter-partials (columns ql*8..ql*8+7 live in every quarter)
    float r0 = a0.x, r1 = a0.y, r2 = a1.x, r3 = a1.y;
    float r4 = a2.x, r5 = a2.y, r6 = a3.x, r7 = a3.y;
#pragma unroll
    for (int m = 16; m <= 32; m <<= 1) {
        r0 += __shfl_xor(r0, m); r1 += __shfl_xor(r1, m);
        r2 += __shfl_xor(r2, m); r3 += __shfl_xor(r3, m);
        r4 += __shfl_xor(r4, m); r5 += __shfl_xor(r5, m);
        r6 += __shfl_xor(r6, m); r7 += __shfl_xor(r7, m);
    }
    if (qg == 0) {
        float dc = dinv[c];
        uint2 o;
        o.x = pack4fp8(dc * r0, dc * r1, dc * r2, dc * r3);
        o.y = pack4fp8(dc * r4, dc * r5, dc * r6, dc * r7);
        ((uint2*)(a + (size_t)c * 32))[ql] = o;   // fp8 row, 128 B
    }
}

// ---------------- MFMA GEMM (fp8 x fp8 -> f32) ----------------

// H8[r][:] = fp8( rowscale_r * relu(A[r][:] @ W + bias) );  rowscale NULL -> 1.
#define RCH 32
__global__ void __launch_bounds__(256, 2) k_gemm(const uint* __restrict__ A,
                                                 const uint2* __restrict__ wfrag,
                                                 const float* __restrict__ bias,
                                                 const float* __restrict__ rowscale,
                                                 uint* __restrict__ H8, int N) {
    __shared__ uint2 sAf[4][2][64];      // [kb][rowgrp][lane], 4 KB
    __shared__ float sEp[4][16][68];     // per-wave epilogue scratch
    int t = threadIdx.x;
    int w = t >> 6;
    int lane = t & 63;
    int rowgrp = w >> 1;
    int colh = w & 1;

    uint2 Bf[4][4];
#pragma unroll
    for (int kb = 0; kb < 4; ++kb)
#pragma unroll
        for (int i = 0; i < 4; ++i)
            Bf[kb][i] = wfrag[(kb * 8 + colh * 4 + i) * 64 + lane];

    float4 bb = ((const float4*)bias)[colh * 16 + (lane & 15)];

    int nchunk = (N + RCH - 1) / RCH;
    for (int ch = blockIdx.x; ch < nchunk; ch += gridDim.x) {
        int r0 = ch * RCH;
        __syncthreads();
        {
            int i = t;                     // 512 uint2 entries, 2 rounds
#pragma unroll
            for (int s = 0; s < 2; ++s, i += 256) {
                int kb = i >> 7;
                int rg = (i >> 6) & 1;
                int ln = i & 63;
                int gr = r0 + rg * 16 + (ln & 15);
                gr = min(gr, N - 1);
                sAf[kb][rg][ln] = ((const uint2*)(A + (size_t)gr * 32))[kb * 4 + (ln >> 4)];
            }
        }
        __syncthreads();

        f32x4 acc[4] = {{0.f, 0.f, 0.f, 0.f}, {0.f, 0.f, 0.f, 0.f},
                        {0.f, 0.f, 0.f, 0.f}, {0.f, 0.f, 0.f, 0.f}};
#pragma unroll
        for (int kb = 0; kb < 4; ++kb) {
            long long af = as_i64(sAf[kb][rowgrp][lane]);
#pragma unroll
            for (int i = 0; i < 4; ++i)
                acc[i] = __builtin_amdgcn_mfma_f32_16x16x32_fp8_fp8(af, as_i64(Bf[kb][i]),
                                                                    acc[i], 0, 0, 0);
        }

#pragma unroll
        for (int i = 0; i < 4; ++i) {
#pragma unroll
            for (int reg = 0; reg < 4; ++reg)
                sEp[w][(lane >> 4) * 4 + reg][i * 16 + (lane & 15)] = acc[i][reg];
        }
#pragma unroll
        for (int e = 0; e < 4; ++e) {
            int rr = (lane >> 4) + 4 * e;   // 0..15
            int cu = lane & 15;
            const float* sp = &sEp[w][rr][cu * 4];
            int rowg = r0 + rowgrp * 16 + rr;
            if (rowg < N) {
                float sc = rowscale ? rowscale[rowg] : 1.0f;
                float o0 = sc * fmaxf(sp[0] + bb.x, 0.f);
                float o1 = sc * fmaxf(sp[1] + bb.y, 0.f);
                float o2 = sc * fmaxf(sp[2] + bb.z, 0.f);
                float o3 = sc * fmaxf(sp[3] + bb.w, 0.f);
                H8[(size_t)rowg * 32 + colh * 16 + cu] = pack4fp8(o0, o1, o2, o3);
            }
        }
    }
}

// ---------------- pooling + classifier ----------------

// 4 blocks/graph x 128 thr = 32 uint-cols x 16 row-segments (round-11 proven).
__global__ void k_pool(const uint* __restrict__ h8, const int* __restrict__ batch,
                       float* __restrict__ gpool, float* __restrict__ gcnt, int N) {
    int gi = blockIdx.x >> 2, part = blockIdx.x & 3;
    int t = threadIdx.x;
    int ui = t & 31;
    int sub = t >> 5;
    int lo = 0, hi = N;
    while (lo < hi) { int m = (lo + hi) >> 1; if (batch[m] < gi) lo = m + 1; else hi = m; }
    int start = lo;
    lo = start; hi = N;
    while (lo < hi) { int m = (lo + hi) >> 1; if (batch[m] <= gi) lo = m + 1; else hi = m; }
    int end = lo;
    if (part == 0 && t == 0) gcnt[gi] = (float)(end - start);
    int len = end - start;
    int q = (len + 15) >> 4;
    int seg = part * 4 + sub;
    int rs = start + seg * q;
    int re = min(end, rs + q);
    float s0 = 0.f, s1 = 0.f, s2 = 0.f, s3 = 0.f;
    for (int i = rs; i < re; ++i) {
        uint qq = h8[(size_t)i * 32 + ui];
        f32x2 lo2 = fp8lo(qq), hi2 = fp8hi(qq);
        s0 += lo2.x; s1 += lo2.y; s2 += hi2.x; s3 += hi2.y;
    }
    if (re > rs) {
        float* gp = gpool + gi * HID + ui * 4;
        atomicAdd(gp + 0, s0);
        atomicAdd(gp + 1, s1);
        atomicAdd(gp + 2, s2);
        atomicAdd(gp + 3, s3);
    }
}

__global__ void k_cls(const float* __restrict__ gpool, const float* __restrict__ gcnt,
                      const float* __restrict__ Wc1, const float* __restrict__ bc1,
                      const float* __restrict__ Wc2, const float* __restrict__ bc2,
                      float* __restrict__ out) {
    int g = blockIdx.x;
    int j = threadIdx.x;  // 64
    float inv = 1.0f / fmaxf(gcnt[g], 1.0f);
    float z = bc1[j];
    for (int k = 0; k < HID; ++k) z = fmaf(gpool[g * HID + k] * inv, Wc1[k * 64 + j], z);
    z = fmaxf(z, 0.f);
    float p = z * Wc2[j];
    for (int off = 32; off; off >>= 1) p += __shfl_down(p, off);
    if (j == 0) out[g] = 1.0f / (1.0f + expf(-(p + bc2[0])));
}

// ---------------- launch ----------------

extern "C" void kernel_launch(void* const* d_in, const int* in_sizes, int n_in,
                              void* d_out, int out_size, void* d_ws, size_t ws_size,
                              hipStream_t stream) {
    const float* x     = (const float*)d_in[0];
    const int*   eidx  = (const int*)d_in[1];
    const int*   batch = (const int*)d_in[2];
    const float* W_emb = (const float*)d_in[3];
    const float* b_emb = (const float*)d_in[4];
    const float* W_gnn = (const float*)d_in[5];
    const float* b_gnn = (const float*)d_in[6];
    const float* W_c1  = (const float*)d_in[7];
    const float* b_c1  = (const float*)d_in[8];
    const float* W_c2  = (const float*)d_in[9];
    const float* b_c2  = (const float*)d_in[10];

    const int N = in_sizes[0];        // 100000
    const int E = in_sizes[1] / 2;    // 3200000
    const int G = out_size;           // 128
    const int* row = eidx;
    const int* col = eidx + E;
    const int NBUK = (N + 511) >> WSH;   // 196 coarse buckets

    char* ws = (char*)d_ws;
    auto alloc = [&](size_t bytes) -> void* {
        void* p = (void*)ws;
        ws += (bytes + 255) & ~(size_t)255;
        return p;
    };
    int*    cnt    = (int*)alloc((size_t)N * 4);
    float*  dinv   = (float*)alloc((size_t)N * 4);
    float2* pk0    = (float2*)alloc((size_t)N * 8);
    int*    bukCur = (int*)alloc(256 * 4);
    uint*   recs   = (uint*)alloc((size_t)NBUK * BUKCAP * 4);  // 19.3 MB
    int*    ebin   = (int*)alloc((size_t)N * CAP * 4);         // 38.4 MB
    float*  u      = (float*)alloc(HID * 4);
    float*  v      = (float*)alloc(HID * 4);
    uint*   G8     = (uint*)alloc((size_t)N * 32 * 4);   // fp8 (dinv-scaled / final H)
    uint*   A      = (uint*)alloc((size_t)N * 32 * 4);   // fp8 aggregate, 12.8 MB
    uint2*  wfrag  = (uint2*)alloc(4096 * 8);            // fp8 B-frags, 2 layers
    float*  gpool  = (float*)alloc((size_t)G * HID * 4);
    float*  gcnt   = (float*)alloc((size_t)G * 4);

    hipMemsetAsync(bukCur, 0, 256 * 4, stream);
    hipMemsetAsync(gpool, 0, (size_t)G * HID * 4, stream);

    // two-phase binning; cnt/dinv/pk0 produced by fused phase B
    k_part<<<(E + TILE - 1) / TILE, 256, 0, stream>>>(row, col, bukCur, recs, E);
    k_fbin<<<NBUK, 256, 0, stream>>>(recs, bukCur, x, cnt, ebin, dinv, pk0, N);

    // fused W-prep (u/v + fp8 MFMA B-fragments)
    k_wprep<<<17, 256, 0, stream>>>(W_emb, b_emb, W_gnn, u, v, wfrag);

    // layer 0: fused scalar-agg + h1 -> g8
    k_sagg<<<(N + 255) / 256, 256, 0, stream>>>(cnt, ebin, x, dinv, pk0, u, v, b_gnn, G8, N);

    // layers 1,2: gather-add agg + fp8 MFMA GEMM.  Layer-1 GEMM pre-scales rows
    // by dinv (output consumed by agg); layer-2 output is plain H (pooling).
    int nchunk = (N + RCH - 1) / RCH;
    int gblk = nchunk < 768 ? nchunk : 768;
    for (int l = 1; l < 3; ++l) {
        k_agg<<<(N + 3) / 4, 256, 0, stream>>>(cnt, ebin, dinv, G8, A, N);
        k_gemm<<<gblk, 256, 0, stream>>>(A, wfrag + (size_t)(l - 1) * 2048,
                                         b_gnn + (size_t)l * HID,
                                         (l == 1) ? dinv : (const float*)nullptr,
                                         G8, N);
    }

    k_pool<<<G * 4, 128, 0, stream>>>(G8, batch, gpool, gcnt, N);
    k_cls<<<G, 64, 0, stream>>>(gpool, gcnt, W_c1, b_c1, W_c2, b_c2, (float*)d_out);
}